// Round 1
// baseline (138.157 us; speedup 1.0000x reference)
//
#include <hip/hip_runtime.h>
#include <hip/hip_bf16.h>
#include <cstddef>
#include <cstdint>

// LinearAttention fused pipeline, MI355X gfx950.
// x:[16,64,64,128] f32, w_qkv:[128,384], w_out:[128,128], b_out/g_ln/b_ln:[128]
// Pipeline:
//   K1: w_qkv -> w_qkv^T bf16
//   K2: qkv = x @ w_qkv (bf16 MFMA 16x16x32, 128x128 tiles, colblock = q|k|v)
//       q-epilogue: softmax over d(32) * 1/sqrt(32) -> qs bf16
//       k-epilogue: exp(k) -> ek bf16   (no max-sub: |k| <= ~4)
//       v-epilogue: -> vv bf16
//   K3: partial ctx[bh][chunk][32][32] = sum_n ek*v, ksum partial (deterministic 2-phase)
//   K4: reduce partials, ctxn = ctx/ksum, W_eff^T[b][j][hd] = sum_e ctxn*w_out (bf16)
//   K5: out = LN( qs @ W_eff[b] + b_out ) (bf16 MFMA + fused LN epilogue)

typedef __attribute__((ext_vector_type(8))) short short8_t;
typedef __attribute__((ext_vector_type(4))) short short4_t;
typedef __attribute__((ext_vector_type(4))) float f32x4;

#define NTOK 4096
#define SCALE_Q 0.17677669529663687f
#define EPS_LN 1e-5f

__device__ __forceinline__ unsigned short f2bf(float f) {
  union { float f; unsigned u; } v; v.f = f;
  unsigned r = (v.u + 0x7FFFu + ((v.u >> 16) & 1u)) >> 16;
  return (unsigned short)r;
}
__device__ __forceinline__ float bf2f(unsigned short u) {
  union { float f; unsigned u; } v; v.u = ((unsigned)u) << 16;
  return v.f;
}

// ---------------- K1: transpose + bf16 convert w_qkv [128][384] -> [384][128]
__global__ void k_transpose_wqkv(const float* __restrict__ w,
                                 unsigned short* __restrict__ wT) {
  int tid = threadIdx.x;
  for (int idx = tid; idx < 128 * 384; idx += 256) {
    int k = idx / 384;
    int c = idx - k * 384;
    wT[c * 128 + k] = f2bf(w[idx]);
  }
}

// ---------------- K2: qkv GEMM + per-part epilogues
__global__ __launch_bounds__(256, 2)
void k_qkv_gemm(const float* __restrict__ x, const unsigned short* __restrict__ wT,
                unsigned short* __restrict__ qs, unsigned short* __restrict__ ek,
                unsigned short* __restrict__ vv) {
  __shared__ short As[128][136];  // x tile, bf16, +8 pad (2-way banks = free)
  __shared__ short Bs[128][136];  // w^T tile (row = out-col, contiguous k)

  int tid = threadIdx.x;
  int cb = blockIdx.x % 3;        // 0=q 1=k 2=v  (consecutive blocks share A tile)
  int rb = blockIdx.x / 3;
  int rowBase = rb * 128;

  { // stage A: 128x128 f32 -> bf16
    const float* xb = x + (size_t)rowBase * 128;
#pragma unroll
    for (int i = 0; i < 16; ++i) {
      int idx = i * 256 + tid;
      int r = idx >> 5;
      int c4 = (idx & 31) << 2;
      float4 f = *(const float4*)(xb + (size_t)r * 128 + c4);
      short4_t s;
      s.x = (short)f2bf(f.x); s.y = (short)f2bf(f.y);
      s.z = (short)f2bf(f.z); s.w = (short)f2bf(f.w);
      *(short4_t*)&As[r][c4] = s;
    }
  }
  { // stage B: wT rows cb*128 .. +127 (already bf16, contiguous 16B)
    const unsigned short* wb = wT + (size_t)cb * 128 * 128;
#pragma unroll
    for (int i = 0; i < 8; ++i) {
      int idx = i * 256 + tid;
      int n = idx >> 4;
      int k8 = (idx & 15) << 3;
      *(short8_t*)&Bs[n][k8] = *(const short8_t*)(wb + (size_t)n * 128 + k8);
    }
  }
  __syncthreads();

  int lane = tid & 63;
  int wv = tid >> 6;
  int wr = wv >> 1, wc = wv & 1;
  int lr = lane & 15;
  int kg = lane >> 4;

  f32x4 acc[4][4] = {};

#pragma unroll
  for (int kk = 0; kk < 128; kk += 32) {
    int k0 = kk + kg * 8;
    short8_t a[4], b[4];
#pragma unroll
    for (int mf = 0; mf < 4; ++mf)
      a[mf] = *(const short8_t*)&As[wr * 64 + mf * 16 + lr][k0];
#pragma unroll
    for (int nf = 0; nf < 4; ++nf)
      b[nf] = *(const short8_t*)&Bs[wc * 64 + nf * 16 + lr][k0];
#pragma unroll
    for (int mf = 0; mf < 4; ++mf)
#pragma unroll
      for (int nf = 0; nf < 4; ++nf)
        acc[mf][nf] = __builtin_amdgcn_mfma_f32_16x16x32_bf16(a[mf], b[nf], acc[mf][nf], 0, 0, 0);
  }

  // C frag mapping (verified): col = 16*nf + lr, row = 16*mf + 4*kg + j
  if (cb == 0) {
    // q: softmax over each head's 32 cols (= nf pair + 16 lanes), * scale
#pragma unroll
    for (int hg = 0; hg < 2; ++hg) {
#pragma unroll
      for (int mf = 0; mf < 4; ++mf) {
#pragma unroll
        for (int j = 0; j < 4; ++j) {
          float v0 = acc[mf][hg * 2][j], v1 = acc[mf][hg * 2 + 1][j];
          float m = fmaxf(v0, v1);
#pragma unroll
          for (int d = 1; d < 16; d <<= 1) m = fmaxf(m, __shfl_xor(m, d, 64));
          float e0 = __expf(v0 - m), e1 = __expf(v1 - m);
          float s = e0 + e1;
#pragma unroll
          for (int d = 1; d < 16; d <<= 1) s += __shfl_xor(s, d, 64);
          float inv = SCALE_Q / s;
          int row = rowBase + wr * 64 + mf * 16 + kg * 4 + j;
          int c0 = wc * 64 + hg * 32 + lr;
          qs[(size_t)row * 128 + c0] = f2bf(e0 * inv);
          qs[(size_t)row * 128 + c0 + 16] = f2bf(e1 * inv);
        }
      }
    }
  } else {
    unsigned short* dst = (cb == 1) ? ek : vv;
    bool isK = (cb == 1);
#pragma unroll
    for (int mf = 0; mf < 4; ++mf) {
      int row = rowBase + wr * 64 + mf * 16 + kg * 4;
#pragma unroll
      for (int nf = 0; nf < 4; ++nf) {
        int col = wc * 64 + nf * 16 + lr;
#pragma unroll
        for (int j = 0; j < 4; ++j) {
          float v = acc[mf][nf][j];
          if (isK) v = __expf(v);
          dst[(size_t)(row + j) * 128 + col] = f2bf(v);
        }
      }
    }
  }
}

// ---------------- K3: partial context (deterministic, no atomics)
// grid 1024 = 64 (b,h) x 16 chunks of 256 tokens
__global__ __launch_bounds__(256, 2)
void k_ctx_partial(const unsigned short* __restrict__ ek, const unsigned short* __restrict__ vv,
                   float* __restrict__ ctxp, float* __restrict__ ksump) {
  __shared__ unsigned short eks[256][32];
  __shared__ unsigned short vs[256][32];
  int tid = threadIdx.x;
  int bh = blockIdx.x >> 4;
  int chunk = blockIdx.x & 15;
  int b = bh >> 2, h = bh & 3;
  size_t rowBase = (size_t)b * NTOK + chunk * 256;
#pragma unroll
  for (int i = 0; i < 4; ++i) {
    int idx = i * 256 + tid;
    int r = idx >> 2;
    int p8 = (idx & 3) << 3;
    size_t g = (rowBase + r) * 128 + h * 32 + p8;
    *(short8_t*)&eks[r][p8] = *(const short8_t*)(ek + g);
    *(short8_t*)&vs[r][p8]  = *(const short8_t*)(vv + g);
  }
  __syncthreads();
  int d = tid >> 3;
  int e0 = (tid & 7) << 2;
  float a0 = 0, a1 = 0, a2 = 0, a3 = 0, ks = 0;
  for (int n = 0; n < 256; ++n) {
    float w = bf2f(eks[n][d]);
    short4_t v4 = *(const short4_t*)&vs[n][e0];
    a0 += w * bf2f((unsigned short)v4.x);
    a1 += w * bf2f((unsigned short)v4.y);
    a2 += w * bf2f((unsigned short)v4.z);
    a3 += w * bf2f((unsigned short)v4.w);
    ks += w;
  }
  size_t o = ((size_t)blockIdx.x * 32 + d) * 32 + e0;
  float4 r4 = make_float4(a0, a1, a2, a3);
  *(float4*)(ctxp + o) = r4;
  if ((tid & 7) == 0) ksump[(size_t)blockIdx.x * 32 + d] = ks;
}

// ---------------- K4: reduce partials + build W_eff^T[b][j][hd] bf16
__global__ __launch_bounds__(256, 1)
void k_weff(const float* __restrict__ ctxp, const float* __restrict__ ksump,
            const float* __restrict__ wout, unsigned short* __restrict__ weffT) {
  __shared__ float wo[128][128];    // 64 KB
  __shared__ float ctxn[4][32][32]; // 16 KB
  __shared__ float ks[4][32];
  int tid = threadIdx.x;
  int b = blockIdx.x;
#pragma unroll
  for (int i = 0; i < 64; ++i) {
    int idx = i * 256 + tid;
    ((float*)wo)[idx] = wout[idx];
  }
  if (tid < 128) {
    int h = tid >> 5, d = tid & 31;
    float s = 0;
    for (int c = 0; c < 16; ++c)
      s += ksump[((size_t)(b * 4 + h) * 16 + c) * 32 + d];
    ks[h][d] = s;
  }
  __syncthreads();
  for (int i = 0; i < 16; ++i) {
    int idx = i * 256 + tid;
    int h = idx >> 10, d = (idx >> 5) & 31, e = idx & 31;
    float s = 0;
    for (int c = 0; c < 16; ++c)
      s += ctxp[(((size_t)(b * 4 + h) * 16 + c) * 32 + d) * 32 + e];
    ctxn[h][d][e] = s / ks[h][d];
  }
  __syncthreads();
  int hd = tid & 127;
  int h = hd >> 5, d = hd & 31;
  int jBase = (tid >> 7) * 64;
  float cx[32];
#pragma unroll
  for (int e = 0; e < 32; ++e) cx[e] = ctxn[h][d][e];
  unsigned short* outp = weffT + (size_t)b * 16384;
  for (int jj = 0; jj < 64; ++jj) {
    int j = jBase + jj;
    float s = 0;
#pragma unroll
    for (int e = 0; e < 32; ++e) s += cx[e] * wo[h * 32 + e][j];
    outp[(size_t)j * 128 + hd] = f2bf(s);
  }
}

// ---------------- K5: final GEMM (qs @ W_eff[b]) + bias + LayerNorm
__global__ __launch_bounds__(256, 2)
void k_out_ln(const unsigned short* __restrict__ qs, const unsigned short* __restrict__ weffT,
              const float* __restrict__ b_out, const float* __restrict__ g_ln,
              const float* __restrict__ b_ln, float* __restrict__ out) {
  __shared__ short As[128][136];
  __shared__ short Bs[128][136];
  __shared__ float2 red[128][2];

  int tid = threadIdx.x;
  int rowBase = blockIdx.x * 128;
  int b = rowBase >> 12;

  {
    const unsigned short* ab = qs + (size_t)rowBase * 128;
#pragma unroll
    for (int i = 0; i < 8; ++i) {
      int idx = i * 256 + tid;
      int r = idx >> 4;
      int k8 = (idx & 15) << 3;
      *(short8_t*)&As[r][k8] = *(const short8_t*)(ab + (size_t)r * 128 + k8);
    }
  }
  {
    const unsigned short* bb = weffT + (size_t)b * 16384;
#pragma unroll
    for (int i = 0; i < 8; ++i) {
      int idx = i * 256 + tid;
      int n = idx >> 4;
      int k8 = (idx & 15) << 3;
      *(short8_t*)&Bs[n][k8] = *(const short8_t*)(bb + (size_t)n * 128 + k8);
    }
  }
  __syncthreads();

  int lane = tid & 63;
  int wv = tid >> 6;
  int wr = wv >> 1, wc = wv & 1;
  int lr = lane & 15;
  int kg = lane >> 4;

  f32x4 acc[4][4] = {};

#pragma unroll
  for (int kk = 0; kk < 128; kk += 32) {
    int k0 = kk + kg * 8;
    short8_t a[4], bfr[4];
#pragma unroll
    for (int mf = 0; mf < 4; ++mf)
      a[mf] = *(const short8_t*)&As[wr * 64 + mf * 16 + lr][k0];
#pragma unroll
    for (int nf = 0; nf < 4; ++nf)
      bfr[nf] = *(const short8_t*)&Bs[wc * 64 + nf * 16 + lr][k0];
#pragma unroll
    for (int mf = 0; mf < 4; ++mf)
#pragma unroll
      for (int nf = 0; nf < 4; ++nf)
        acc[mf][nf] = __builtin_amdgcn_mfma_f32_16x16x32_bf16(a[mf], bfr[nf], acc[mf][nf], 0, 0, 0);
  }

  int colc[4]; float bo[4], gl[4], bl[4];
#pragma unroll
  for (int nf = 0; nf < 4; ++nf) {
    int c = wc * 64 + nf * 16 + lr;
    colc[nf] = c; bo[nf] = b_out[c]; gl[nf] = g_ln[c]; bl[nf] = b_ln[c];
  }
#pragma unroll
  for (int mf = 0; mf < 4; ++mf)
#pragma unroll
    for (int nf = 0; nf < 4; ++nf)
#pragma unroll
      for (int j = 0; j < 4; ++j) acc[mf][nf][j] += bo[nf];

#pragma unroll
  for (int mf = 0; mf < 4; ++mf) {
    float s[4] = {0, 0, 0, 0}, q[4] = {0, 0, 0, 0};
#pragma unroll
    for (int nf = 0; nf < 4; ++nf)
#pragma unroll
      for (int j = 0; j < 4; ++j) {
        float v = acc[mf][nf][j];
        s[j] += v; q[j] += v * v;
      }
#pragma unroll
    for (int j = 0; j < 4; ++j) {
#pragma unroll
      for (int d = 1; d < 16; d <<= 1) {
        s[j] += __shfl_xor(s[j], d, 64);
        q[j] += __shfl_xor(q[j], d, 64);
      }
    }
    if (lr == 0) {
#pragma unroll
      for (int j = 0; j < 4; ++j)
        red[wr * 64 + mf * 16 + kg * 4 + j][wc] = make_float2(s[j], q[j]);
    }
  }
  __syncthreads();
#pragma unroll
  for (int mf = 0; mf < 4; ++mf) {
#pragma unroll
    for (int j = 0; j < 4; ++j) {
      int rloc = wr * 64 + mf * 16 + kg * 4 + j;
      float2 r0 = red[rloc][0], r1 = red[rloc][1];
      float mean = (r0.x + r1.x) * (1.0f / 128.0f);
      float var = (r0.y + r1.y) * (1.0f / 128.0f) - mean * mean;
      float rstd = rsqrtf(var + EPS_LN);
      size_t ro = (size_t)(rowBase + rloc) * 128;
#pragma unroll
      for (int nf = 0; nf < 4; ++nf)
        out[ro + colc[nf]] = (acc[mf][nf][j] - mean) * rstd * gl[nf] + bl[nf];
    }
  }
}

extern "C" void kernel_launch(void* const* d_in, const int* in_sizes, int n_in,
                              void* d_out, int out_size, void* d_ws, size_t ws_size,
                              hipStream_t stream) {
  const float* x     = (const float*)d_in[0];
  const float* w_qkv = (const float*)d_in[1];
  const float* w_out = (const float*)d_in[2];
  const float* b_out = (const float*)d_in[3];
  const float* g_ln  = (const float*)d_in[4];
  const float* b_ln  = (const float*)d_in[5];
  float* out = (float*)d_out;

  char* ws = (char*)d_ws;
  unsigned short* qs    = (unsigned short*)(ws + 0);          // 16 MB bf16 [65536][128]
  unsigned short* ek    = (unsigned short*)(ws + 16777216);   // 16 MB
  unsigned short* vv    = (unsigned short*)(ws + 33554432);   // 16 MB
  unsigned short* wqkvT = (unsigned short*)(ws + 50331648);   // 96 KB bf16 [384][128]
  float* ctxp           = (float*)(ws + 50429952);            // 4 MB  [64][16][32][32]
  float* ksump          = (float*)(ws + 54624256);            // 128 KB [64][16][32]
  unsigned short* weffT = (unsigned short*)(ws + 54755328);   // 512 KB bf16 [16][128][128]

  k_transpose_wqkv<<<1, 256, 0, stream>>>(w_qkv, wqkvT);
  k_qkv_gemm<<<1536, 256, 0, stream>>>(x, wqkvT, qs, ek, vv);
  k_ctx_partial<<<1024, 256, 0, stream>>>(ek, vv, ctxp, ksump);
  k_weff<<<16, 256, 0, stream>>>(ctxp, ksump, w_out, weffT);
  k_out_ln<<<512, 256, 0, stream>>>(qs, weffT, b_out, g_ln, b_ln, out);
}

// Round 2
// 98.986 us; speedup vs baseline: 1.3957x; 1.3957x over previous
//
#include <hip/hip_runtime.h>
#include <hip/hip_bf16.h>
#include <cstddef>
#include <cstdint>

// LinearAttention fused pipeline, MI355X gfx950.
// x:[16,64,64,128] f32, w_qkv:[128,384], w_out:[128,128], b_out/g_ln/b_ln:[128]
// Pipeline:
//   K1: w_qkv -> w_qkv^T bf16 (grid-parallel)
//   K2: qkv = x @ w_qkv (bf16 MFMA 16x16x32). A-frags direct from global f32
//       with v_perm truncation-pack (no A LDS, 1 barrier, 34KB LDS).
//       q-epilogue: softmax over d(32) * 1/sqrt(32) -> qs bf16
//       k-epilogue: exp(k) -> ek bf16   (no max-sub: |k| <= ~4)
//       v-epilogue: -> vv bf16
//   K3: partial ctx[bh][chunk][32][32] = sum_n ek*v, ksum partial (deterministic)
//   K4: reduce partials, ctxn = ctx/ksum, W_eff^T[b][j][hd] = sum_e ctxn*w_out (bf16)
//   K5: out = LN( qs @ W_eff[b] + b_out ). A-frags direct from qs (bf16, no LDS).

typedef __attribute__((ext_vector_type(8))) short short8_t;
typedef __attribute__((ext_vector_type(4))) short short4_t;
typedef __attribute__((ext_vector_type(4))) float f32x4;

#define NTOK 4096
#define SCALE_Q 0.17677669529663687f
#define EPS_LN 1e-5f

__device__ __forceinline__ unsigned short f2bf(float f) {
  union { float f; unsigned u; } v; v.f = f;
  unsigned r = (v.u + 0x7FFFu + ((v.u >> 16) & 1u)) >> 16;
  return (unsigned short)r;
}
__device__ __forceinline__ float bf2f(unsigned short u) {
  union { float f; unsigned u; } v; v.u = ((unsigned)u) << 16;
  return v.f;
}

// pack 8 f32 -> 8 bf16 by truncation: 4x v_perm_b32 (vs ~32 VALU for RNE)
__device__ __forceinline__ short8_t trunc8(float4 lo, float4 hi) {
  union { float4 f; unsigned u[4]; } a, b;
  union { unsigned u[4]; short8_t s; } r;
  a.f = lo; b.f = hi;
  r.u[0] = __builtin_amdgcn_perm(a.u[1], a.u[0], 0x07060302);
  r.u[1] = __builtin_amdgcn_perm(a.u[3], a.u[2], 0x07060302);
  r.u[2] = __builtin_amdgcn_perm(b.u[1], b.u[0], 0x07060302);
  r.u[3] = __builtin_amdgcn_perm(b.u[3], b.u[2], 0x07060302);
  return r.s;
}

// ---------------- K1: transpose + bf16 convert w_qkv [128][384] -> [384][128]
// grid 192 x 256 (was 1 block = 74us latency-bound)
__global__ void k_transpose_wqkv(const float* __restrict__ w,
                                 unsigned short* __restrict__ wT) {
  int idx = blockIdx.x * 256 + threadIdx.x;   // 49152 total
  int k = idx / 384;
  int c = idx - k * 384;
  wT[c * 128 + k] = f2bf(w[idx]);
}

// ---------------- K2: qkv GEMM + per-part epilogues
__global__ __launch_bounds__(256, 2)
void k_qkv_gemm(const float* __restrict__ x, const unsigned short* __restrict__ wT,
                unsigned short* __restrict__ qs, unsigned short* __restrict__ ek,
                unsigned short* __restrict__ vv) {
  __shared__ short Bs[128][136];  // w^T tile only (34 KB)

  int tid = threadIdx.x;
  int cb = blockIdx.x % 3;        // 0=q 1=k 2=v (consecutive blocks share x tile in L2)
  int rb = blockIdx.x / 3;
  int rowBase = rb * 128;

  { // stage B: wT rows cb*128 .. +127 (bf16, contiguous 16B)
    const unsigned short* wb = wT + (size_t)cb * 128 * 128;
#pragma unroll
    for (int i = 0; i < 8; ++i) {
      int idx = i * 256 + tid;
      int n = idx >> 4;
      int k8 = (idx & 15) << 3;
      *(short8_t*)&Bs[n][k8] = *(const short8_t*)(wb + (size_t)n * 128 + k8);
    }
  }

  int lane = tid & 63;
  int wv = tid >> 6;
  int wr = wv >> 1, wc = wv & 1;
  int lr = lane & 15;
  int kg = lane >> 4;

  // A fragment pointers: row = rowBase + wr*64 + mf*16 + lr, k offset kg*8
  const float* ap[4];
#pragma unroll
  for (int mf = 0; mf < 4; ++mf)
    ap[mf] = x + (size_t)(rowBase + wr * 64 + mf * 16 + lr) * 128 + kg * 8;

  float4 cur[4][2];
#pragma unroll
  for (int mf = 0; mf < 4; ++mf) {
    cur[mf][0] = *(const float4*)(ap[mf]);
    cur[mf][1] = *(const float4*)(ap[mf] + 4);
  }
  __syncthreads();   // Bs ready (A loads overlap the barrier)

  f32x4 acc[4][4] = {};
#pragma unroll
  for (int kk = 0; kk < 4; ++kk) {
    short8_t a[4], b[4];
#pragma unroll
    for (int mf = 0; mf < 4; ++mf) a[mf] = trunc8(cur[mf][0], cur[mf][1]);
    if (kk < 3) {  // prefetch next k-step while MFMAs run
#pragma unroll
      for (int mf = 0; mf < 4; ++mf) {
        cur[mf][0] = *(const float4*)(ap[mf] + (kk + 1) * 32);
        cur[mf][1] = *(const float4*)(ap[mf] + (kk + 1) * 32 + 4);
      }
    }
#pragma unroll
    for (int nf = 0; nf < 4; ++nf)
      b[nf] = *(const short8_t*)&Bs[wc * 64 + nf * 16 + lr][kk * 32 + kg * 8];
#pragma unroll
    for (int mf = 0; mf < 4; ++mf)
#pragma unroll
      for (int nf = 0; nf < 4; ++nf)
        acc[mf][nf] = __builtin_amdgcn_mfma_f32_16x16x32_bf16(a[mf], b[nf], acc[mf][nf], 0, 0, 0);
  }

  // C frag mapping (verified): col = 16*nf + lr, row = 16*mf + 4*kg + j
  if (cb == 0) {
    // q: softmax over each head's 32 cols (= nf pair + 16 lanes), * scale
#pragma unroll
    for (int hg = 0; hg < 2; ++hg) {
#pragma unroll
      for (int mf = 0; mf < 4; ++mf) {
#pragma unroll
        for (int j = 0; j < 4; ++j) {
          float v0 = acc[mf][hg * 2][j], v1 = acc[mf][hg * 2 + 1][j];
          float m = fmaxf(v0, v1);
#pragma unroll
          for (int d = 1; d < 16; d <<= 1) m = fmaxf(m, __shfl_xor(m, d, 64));
          float e0 = __expf(v0 - m), e1 = __expf(v1 - m);
          float s = e0 + e1;
#pragma unroll
          for (int d = 1; d < 16; d <<= 1) s += __shfl_xor(s, d, 64);
          float inv = SCALE_Q / s;
          int row = rowBase + wr * 64 + mf * 16 + kg * 4 + j;
          int c0 = wc * 64 + hg * 32 + lr;
          qs[(size_t)row * 128 + c0] = f2bf(e0 * inv);
          qs[(size_t)row * 128 + c0 + 16] = f2bf(e1 * inv);
        }
      }
    }
  } else {
    unsigned short* dst = (cb == 1) ? ek : vv;
    bool isK = (cb == 1);
#pragma unroll
    for (int mf = 0; mf < 4; ++mf) {
      int row = rowBase + wr * 64 + mf * 16 + kg * 4;
#pragma unroll
      for (int nf = 0; nf < 4; ++nf) {
        int col = wc * 64 + nf * 16 + lr;
#pragma unroll
        for (int j = 0; j < 4; ++j) {
          float v = acc[mf][nf][j];
          if (isK) v = __expf(v);
          dst[(size_t)(row + j) * 128 + col] = f2bf(v);
        }
      }
    }
  }
}

// ---------------- K3: partial context (deterministic, no atomics)
// grid 1024 = 64 (b,h) x 16 chunks of 256 tokens
__global__ __launch_bounds__(256, 2)
void k_ctx_partial(const unsigned short* __restrict__ ek, const unsigned short* __restrict__ vv,
                   float* __restrict__ ctxp, float* __restrict__ ksump) {
  __shared__ unsigned short eks[256][32];
  __shared__ unsigned short vs[256][32];
  int tid = threadIdx.x;
  int bh = blockIdx.x >> 4;
  int chunk = blockIdx.x & 15;
  int b = bh >> 2, h = bh & 3;
  size_t rowBase = (size_t)b * NTOK + chunk * 256;
#pragma unroll
  for (int i = 0; i < 4; ++i) {
    int idx = i * 256 + tid;
    int r = idx >> 2;
    int p8 = (idx & 3) << 3;
    size_t g = (rowBase + r) * 128 + h * 32 + p8;
    *(short8_t*)&eks[r][p8] = *(const short8_t*)(ek + g);
    *(short8_t*)&vs[r][p8]  = *(const short8_t*)(vv + g);
  }
  __syncthreads();
  int d = tid >> 3;
  int e0 = (tid & 7) << 2;
  float a0 = 0, a1 = 0, a2 = 0, a3 = 0, ks = 0;
  for (int n = 0; n < 256; ++n) {
    float w = bf2f(eks[n][d]);
    short4_t v4 = *(const short4_t*)&vs[n][e0];
    a0 += w * bf2f((unsigned short)v4.x);
    a1 += w * bf2f((unsigned short)v4.y);
    a2 += w * bf2f((unsigned short)v4.z);
    a3 += w * bf2f((unsigned short)v4.w);
    ks += w;
  }
  size_t o = ((size_t)blockIdx.x * 32 + d) * 32 + e0;
  float4 r4 = make_float4(a0, a1, a2, a3);
  *(float4*)(ctxp + o) = r4;
  if ((tid & 7) == 0) ksump[(size_t)blockIdx.x * 32 + d] = ks;
}

// ---------------- K4: reduce partials + build W_eff^T[b][j][hd] bf16
__global__ __launch_bounds__(256, 1)
void k_weff(const float* __restrict__ ctxp, const float* __restrict__ ksump,
            const float* __restrict__ wout, unsigned short* __restrict__ weffT) {
  __shared__ float wo[128][128];    // 64 KB
  __shared__ float ctxn[4][32][32]; // 16 KB
  __shared__ float ks[4][32];
  int tid = threadIdx.x;
  int b = blockIdx.x;
#pragma unroll
  for (int i = 0; i < 64; ++i) {
    int idx = i * 256 + tid;
    ((float*)wo)[idx] = wout[idx];
  }
  if (tid < 128) {
    int h = tid >> 5, d = tid & 31;
    float s = 0;
    for (int c = 0; c < 16; ++c)
      s += ksump[((size_t)(b * 4 + h) * 16 + c) * 32 + d];
    ks[h][d] = s;
  }
  __syncthreads();
  for (int i = 0; i < 16; ++i) {
    int idx = i * 256 + tid;
    int h = idx >> 10, d = (idx >> 5) & 31, e = idx & 31;
    float s = 0;
    for (int c = 0; c < 16; ++c)
      s += ctxp[(((size_t)(b * 4 + h) * 16 + c) * 32 + d) * 32 + e];
    ctxn[h][d][e] = s / ks[h][d];
  }
  __syncthreads();
  int hd = tid & 127;
  int h = hd >> 5, d = hd & 31;
  int jBase = (tid >> 7) * 64;
  float cx[32];
#pragma unroll
  for (int e = 0; e < 32; ++e) cx[e] = ctxn[h][d][e];
  unsigned short* outp = weffT + (size_t)b * 16384;
  for (int jj = 0; jj < 64; ++jj) {
    int j = jBase + jj;
    float s = 0;
#pragma unroll
    for (int e = 0; e < 32; ++e) s += cx[e] * wo[h * 32 + e][j];
    outp[(size_t)j * 128 + hd] = f2bf(s);
  }
}

// ---------------- K5: final GEMM (qs @ W_eff[b]) + bias + LayerNorm
__global__ __launch_bounds__(256, 2)
void k_out_ln(const unsigned short* __restrict__ qs, const unsigned short* __restrict__ weffT,
              const float* __restrict__ b_out, const float* __restrict__ g_ln,
              const float* __restrict__ b_ln, float* __restrict__ out) {
  __shared__ short Bs[128][136];
  __shared__ float2 red[128][2];

  int tid = threadIdx.x;
  int rowBase = blockIdx.x * 128;
  int b = rowBase >> 12;

  {
    const unsigned short* bb = weffT + (size_t)b * 16384;
#pragma unroll
    for (int i = 0; i < 8; ++i) {
      int idx = i * 256 + tid;
      int n = idx >> 4;
      int k8 = (idx & 15) << 3;
      *(short8_t*)&Bs[n][k8] = *(const short8_t*)(bb + (size_t)n * 128 + k8);
    }
  }

  int lane = tid & 63;
  int wv = tid >> 6;
  int wr = wv >> 1, wc = wv & 1;
  int lr = lane & 15;
  int kg = lane >> 4;

  // A fragments direct from qs (already bf16, no conversion, no LDS)
  short8_t a[4][4];  // [kk][mf]
  {
    const unsigned short* ab = qs + (size_t)rowBase * 128 + kg * 8;
#pragma unroll
    for (int mf = 0; mf < 4; ++mf) {
      const unsigned short* ar = ab + (size_t)(wr * 64 + mf * 16 + lr) * 128;
#pragma unroll
      for (int kk = 0; kk < 4; ++kk)
        a[kk][mf] = *(const short8_t*)(ar + kk * 32);
    }
  }
  __syncthreads();

  f32x4 acc[4][4] = {};
#pragma unroll
  for (int kk = 0; kk < 4; ++kk) {
    short8_t bfr[4];
#pragma unroll
    for (int nf = 0; nf < 4; ++nf)
      bfr[nf] = *(const short8_t*)&Bs[wc * 64 + nf * 16 + lr][kk * 32 + kg * 8];
#pragma unroll
    for (int mf = 0; mf < 4; ++mf)
#pragma unroll
      for (int nf = 0; nf < 4; ++nf)
        acc[mf][nf] = __builtin_amdgcn_mfma_f32_16x16x32_bf16(a[kk][mf], bfr[nf], acc[mf][nf], 0, 0, 0);
  }

  int colc[4]; float bo[4], gl[4], bl[4];
#pragma unroll
  for (int nf = 0; nf < 4; ++nf) {
    int c = wc * 64 + nf * 16 + lr;
    colc[nf] = c; bo[nf] = b_out[c]; gl[nf] = g_ln[c]; bl[nf] = b_ln[c];
  }
#pragma unroll
  for (int mf = 0; mf < 4; ++mf)
#pragma unroll
    for (int nf = 0; nf < 4; ++nf)
#pragma unroll
      for (int j = 0; j < 4; ++j) acc[mf][nf][j] += bo[nf];

#pragma unroll
  for (int mf = 0; mf < 4; ++mf) {
    float s[4] = {0, 0, 0, 0}, q[4] = {0, 0, 0, 0};
#pragma unroll
    for (int nf = 0; nf < 4; ++nf)
#pragma unroll
      for (int j = 0; j < 4; ++j) {
        float v = acc[mf][nf][j];
        s[j] += v; q[j] += v * v;
      }
#pragma unroll
    for (int j = 0; j < 4; ++j) {
#pragma unroll
      for (int d = 1; d < 16; d <<= 1) {
        s[j] += __shfl_xor(s[j], d, 64);
        q[j] += __shfl_xor(q[j], d, 64);
      }
    }
    if (lr == 0) {
#pragma unroll
      for (int j = 0; j < 4; ++j)
        red[wr * 64 + mf * 16 + kg * 4 + j][wc] = make_float2(s[j], q[j]);
    }
  }
  __syncthreads();
#pragma unroll
  for (int mf = 0; mf < 4; ++mf) {
#pragma unroll
    for (int j = 0; j < 4; ++j) {
      int rloc = wr * 64 + mf * 16 + kg * 4 + j;
      float2 r0 = red[rloc][0], r1 = red[rloc][1];
      float mean = (r0.x + r1.x) * (1.0f / 128.0f);
      float var = (r0.y + r1.y) * (1.0f / 128.0f) - mean * mean;
      float rstd = rsqrtf(var + EPS_LN);
      size_t ro = (size_t)(rowBase + rloc) * 128;
#pragma unroll
      for (int nf = 0; nf < 4; ++nf)
        out[ro + colc[nf]] = (acc[mf][nf][j] - mean) * rstd * gl[nf] + bl[nf];
    }
  }
}

extern "C" void kernel_launch(void* const* d_in, const int* in_sizes, int n_in,
                              void* d_out, int out_size, void* d_ws, size_t ws_size,
                              hipStream_t stream) {
  const float* x     = (const float*)d_in[0];
  const float* w_qkv = (const float*)d_in[1];
  const float* w_out = (const float*)d_in[2];
  const float* b_out = (const float*)d_in[3];
  const float* g_ln  = (const float*)d_in[4];
  const float* b_ln  = (const float*)d_in[5];
  float* out = (float*)d_out;

  char* ws = (char*)d_ws;
  unsigned short* qs    = (unsigned short*)(ws + 0);          // 16 MB bf16 [65536][128]
  unsigned short* ek    = (unsigned short*)(ws + 16777216);   // 16 MB
  unsigned short* vv    = (unsigned short*)(ws + 33554432);   // 16 MB
  unsigned short* wqkvT = (unsigned short*)(ws + 50331648);   // 96 KB bf16 [384][128]
  float* ctxp           = (float*)(ws + 50429952);            // 4 MB  [64][16][32][32]
  float* ksump          = (float*)(ws + 54624256);            // 128 KB [64][16][32]
  unsigned short* weffT = (unsigned short*)(ws + 54755328);   // 512 KB bf16 [16][128][128]

  k_transpose_wqkv<<<192, 256, 0, stream>>>(w_qkv, wqkvT);
  k_qkv_gemm<<<1536, 256, 0, stream>>>(x, wqkvT, qs, ek, vv);
  k_ctx_partial<<<1024, 256, 0, stream>>>(ek, vv, ctxp, ksump);
  k_weff<<<16, 256, 0, stream>>>(ctxp, ksump, w_out, weffT);
  k_out_ln<<<512, 256, 0, stream>>>(qs, weffT, b_out, g_ln, b_ln, out);
}

// Round 3
// 69.638 us; speedup vs baseline: 1.9839x; 1.4214x over previous
//
#include <hip/hip_runtime.h>
#include <hip/hip_bf16.h>
#include <cstddef>
#include <cstdint>

// LinearAttention fused pipeline, MI355X gfx950.
// x:[16,64,64,128] f32, w_qkv:[128,384], w_out:[128,128], b_out/g_ln/b_ln:[128]
// Pipeline (4 kernels, no qkv intermediates in HBM):
//   K1 k_transpose_wqkv: w_qkv -> w_qkv^T bf16
//   K2 k_kv_ctx: per 128-token tile: k GEMM + v GEMM (shared A-frags),
//      exp(k), LDS transpose -> per-head ctx[32][32] partial via MFMA + ksum.
//      Writes only ctx partials (8 MB) + ksum partials.
//   K3 k_weff: reduce partials, ctxn = ctx/ksum, W_eff^T[b][j][hd] bf16.
//   K4 k_qout_ln: q GEMM + softmax(d)*scale -> LDS -> GEMM2 with W_eff[b]
//      + bias + LayerNorm, store out. qs never hits HBM.

typedef __attribute__((ext_vector_type(8))) short short8_t;
typedef __attribute__((ext_vector_type(4))) short short4_t;
typedef __attribute__((ext_vector_type(4))) float f32x4;

#define SCALE_Q 0.17677669529663687f
#define EPS_LN 1e-5f

__device__ __forceinline__ unsigned short f2bf(float f) {
  union { float f; unsigned u; } v; v.f = f;
  unsigned r = (v.u + 0x7FFFu + ((v.u >> 16) & 1u)) >> 16;
  return (unsigned short)r;
}
__device__ __forceinline__ float bf2f(unsigned short u) {
  union { float f; unsigned u; } v; v.u = ((unsigned)u) << 16;
  return v.f;
}

// pack 8 f32 -> 8 bf16 by truncation: 4x v_perm_b32
__device__ __forceinline__ short8_t trunc8(float4 lo, float4 hi) {
  union { float4 f; unsigned u[4]; } a, b;
  union { unsigned u[4]; short8_t s; } r;
  a.f = lo; b.f = hi;
  r.u[0] = __builtin_amdgcn_perm(a.u[1], a.u[0], 0x07060302);
  r.u[1] = __builtin_amdgcn_perm(a.u[3], a.u[2], 0x07060302);
  r.u[2] = __builtin_amdgcn_perm(b.u[1], b.u[0], 0x07060302);
  r.u[3] = __builtin_amdgcn_perm(b.u[3], b.u[2], 0x07060302);
  return r.s;
}

// ---------------- K1: transpose + bf16 convert w_qkv [128][384] -> [384][128]
__global__ void k_transpose_wqkv(const float* __restrict__ w,
                                 unsigned short* __restrict__ wT) {
  int idx = blockIdx.x * 256 + threadIdx.x;   // 49152 total
  int k = idx / 384;
  int c = idx - k * 384;
  wT[c * 128 + k] = f2bf(w[idx]);
}

// ---------------- K2: k+v GEMMs + in-tile ctx partial (no ek/vv to HBM)
// grid 512 (one per 128-token tile). ctxp[blk][h][32][32] f32, ksump[blk][128].
__global__ __launch_bounds__(256, 2)
void k_kv_ctx(const float* __restrict__ x, const unsigned short* __restrict__ wT,
              float* __restrict__ ctxp, float* __restrict__ ksump) {
  __shared__ short Bk[128][136];  // k weights; later reused as ekT[col d][token]
  __shared__ short Bv[128][136];  // v weights; later reused as vT[col e][token]

  int tid = threadIdx.x;
  int rb = blockIdx.x;
  int rowBase = rb * 128;

  { // stage Bk, Bv from wT parts 1 and 2
    const unsigned short* wk = wT + (size_t)1 * 128 * 128;
    const unsigned short* wv2 = wT + (size_t)2 * 128 * 128;
#pragma unroll
    for (int i = 0; i < 8; ++i) {
      int idx = i * 256 + tid;
      int n = idx >> 4;
      int k8 = (idx & 15) << 3;
      *(short8_t*)&Bk[n][k8] = *(const short8_t*)(wk + (size_t)n * 128 + k8);
      *(short8_t*)&Bv[n][k8] = *(const short8_t*)(wv2 + (size_t)n * 128 + k8);
    }
  }

  int lane = tid & 63;
  int wv = tid >> 6;
  int wr = wv >> 1, wc = wv & 1;
  int lr = lane & 15;
  int kg = lane >> 4;

  // A fragments: load x f32 and convert once; reused by both GEMMs
  short8_t abf[4][4];  // [kk][mf]
  {
    const float* ap = x + (size_t)(rowBase + wr * 64 + lr) * 128 + kg * 8;
#pragma unroll
    for (int mf = 0; mf < 4; ++mf) {
      const float* r = ap + (size_t)mf * 16 * 128;
#pragma unroll
      for (int kk = 0; kk < 4; ++kk)
        abf[kk][mf] = trunc8(*(const float4*)(r + kk * 32),
                             *(const float4*)(r + kk * 32 + 4));
    }
  }
  __syncthreads();  // Bk/Bv staged

  // k GEMM -> exp -> packed bf16 (4 tokens per uint2)
  uint2 ekp[4][4], vp[4][4];
  {
    f32x4 acc[4][4] = {};
#pragma unroll
    for (int kk = 0; kk < 4; ++kk) {
      short8_t bf[4];
#pragma unroll
      for (int nf = 0; nf < 4; ++nf)
        bf[nf] = *(const short8_t*)&Bk[wc * 64 + nf * 16 + lr][kk * 32 + kg * 8];
#pragma unroll
      for (int mf = 0; mf < 4; ++mf)
#pragma unroll
        for (int nf = 0; nf < 4; ++nf)
          acc[mf][nf] = __builtin_amdgcn_mfma_f32_16x16x32_bf16(abf[kk][mf], bf[nf], acc[mf][nf], 0, 0, 0);
    }
#pragma unroll
    for (int mf = 0; mf < 4; ++mf)
#pragma unroll
      for (int nf = 0; nf < 4; ++nf) {
        unsigned s0 = f2bf(__expf(acc[mf][nf][0])), s1 = f2bf(__expf(acc[mf][nf][1]));
        unsigned s2 = f2bf(__expf(acc[mf][nf][2])), s3 = f2bf(__expf(acc[mf][nf][3]));
        ekp[mf][nf].x = s0 | (s1 << 16);
        ekp[mf][nf].y = s2 | (s3 << 16);
      }
  }
  // v GEMM -> packed bf16
  {
    f32x4 acc[4][4] = {};
#pragma unroll
    for (int kk = 0; kk < 4; ++kk) {
      short8_t bf[4];
#pragma unroll
      for (int nf = 0; nf < 4; ++nf)
        bf[nf] = *(const short8_t*)&Bv[wc * 64 + nf * 16 + lr][kk * 32 + kg * 8];
#pragma unroll
      for (int mf = 0; mf < 4; ++mf)
#pragma unroll
        for (int nf = 0; nf < 4; ++nf)
          acc[mf][nf] = __builtin_amdgcn_mfma_f32_16x16x32_bf16(abf[kk][mf], bf[nf], acc[mf][nf], 0, 0, 0);
    }
#pragma unroll
    for (int mf = 0; mf < 4; ++mf)
#pragma unroll
      for (int nf = 0; nf < 4; ++nf) {
        unsigned s0 = f2bf(acc[mf][nf][0]), s1 = f2bf(acc[mf][nf][1]);
        unsigned s2 = f2bf(acc[mf][nf][2]), s3 = f2bf(acc[mf][nf][3]);
        vp[mf][nf].x = s0 | (s1 << 16);
        vp[mf][nf].y = s2 | (s3 << 16);
      }
  }
  __syncthreads();  // all waves done reading Bk/Bv

  // transposed LDS write: ekT[col][token], vT[col][token]
  short (*ekT)[136] = Bk;
  short (*vT)[136] = Bv;
#pragma unroll
  for (int mf = 0; mf < 4; ++mf) {
    int t0 = wr * 64 + mf * 16 + kg * 4;  // 4 consecutive tokens
#pragma unroll
    for (int nf = 0; nf < 4; ++nf) {
      int col = wc * 64 + nf * 16 + lr;
      *(uint2*)&ekT[col][t0] = ekp[mf][nf];
      *(uint2*)&vT[col][t0] = vp[mf][nf];
    }
  }
  __syncthreads();

  // per-head ctx MFMA: wave wv handles head wv. ctx[d][e] = sum_n ekT[d][n]*vT[e][n]
  {
    int h = wv;
    f32x4 c2[2][2] = {};
#pragma unroll
    for (int kk = 0; kk < 4; ++kk) {
      short8_t a2[2], b2[2];
#pragma unroll
      for (int m2 = 0; m2 < 2; ++m2)
        a2[m2] = *(const short8_t*)&ekT[h * 32 + m2 * 16 + lr][kk * 32 + kg * 8];
#pragma unroll
      for (int n2 = 0; n2 < 2; ++n2)
        b2[n2] = *(const short8_t*)&vT[h * 32 + n2 * 16 + lr][kk * 32 + kg * 8];
#pragma unroll
      for (int m2 = 0; m2 < 2; ++m2)
#pragma unroll
        for (int n2 = 0; n2 < 2; ++n2)
          c2[m2][n2] = __builtin_amdgcn_mfma_f32_16x16x32_bf16(a2[m2], b2[n2], c2[m2][n2], 0, 0, 0);
    }
    float* cp = ctxp + ((size_t)rb * 4 + h) * 1024;
#pragma unroll
    for (int m2 = 0; m2 < 2; ++m2)
#pragma unroll
      for (int n2 = 0; n2 < 2; ++n2)
#pragma unroll
        for (int j = 0; j < 4; ++j) {
          int d = m2 * 16 + kg * 4 + j;
          int e = n2 * 16 + lr;
          cp[d * 32 + e] = c2[m2][n2][j];
        }
  }

  // ksum partial: threads 0..127 sum ekT[col][0..127]
  if (tid < 128) {
    float s = 0;
#pragma unroll
    for (int t8 = 0; t8 < 128; t8 += 8) {
      short8_t v8 = *(const short8_t*)&ekT[tid][t8];
#pragma unroll
      for (int i = 0; i < 8; ++i) s += bf2f((unsigned short)v8[i]);
    }
    ksump[(size_t)rb * 128 + tid] = s;
  }
}

// ---------------- K3: reduce partials + build W_eff^T[b][j][hd] bf16
__global__ __launch_bounds__(256, 1)
void k_weff(const float* __restrict__ ctxp, const float* __restrict__ ksump,
            const float* __restrict__ wout, unsigned short* __restrict__ weffT) {
  __shared__ float wo[128][128];    // 64 KB
  __shared__ float ctxn[4][32][32]; // 16 KB
  __shared__ float ks[4][32];
  int tid = threadIdx.x;
  int b = blockIdx.x;
#pragma unroll
  for (int i = 0; i < 64; ++i) {
    int idx = i * 256 + tid;
    ((float*)wo)[idx] = wout[idx];
  }
  if (tid < 128) {
    int h = tid >> 5, d = tid & 31;
    float s = 0;
    for (int c = 0; c < 32; ++c)
      s += ksump[((size_t)(b * 32 + c)) * 128 + tid];
    ks[h][d] = s;
  }
  __syncthreads();
  for (int i = 0; i < 16; ++i) {
    int idx = i * 256 + tid;
    int h = idx >> 10, d = (idx >> 5) & 31;
    float s = 0;
    for (int c = 0; c < 32; ++c)
      s += ctxp[(((size_t)(b * 32 + c) * 4 + h) << 10) + (idx & 1023)];
    ctxn[h][d][idx & 31] = s / ks[h][d];
  }
  __syncthreads();
  int hd = tid & 127;
  int h = hd >> 5, d = hd & 31;
  int jBase = (tid >> 7) * 64;
  float cx[32];
#pragma unroll
  for (int e = 0; e < 32; ++e) cx[e] = ctxn[h][d][e];
  unsigned short* outp = weffT + (size_t)b * 16384;
  for (int jj = 0; jj < 64; ++jj) {
    int j = jBase + jj;
    float s = 0;
#pragma unroll
    for (int e = 0; e < 32; ++e) s += cx[e] * wo[h * 32 + e][j];
    outp[(size_t)j * 128 + hd] = f2bf(s);
  }
}

// ---------------- K4: q GEMM + softmax -> LDS -> GEMM2(W_eff) + bias + LN
__global__ __launch_bounds__(256, 2)
void k_qout_ln(const float* __restrict__ x, const unsigned short* __restrict__ wT,
               const unsigned short* __restrict__ weffT,
               const float* __restrict__ b_out, const float* __restrict__ g_ln,
               const float* __restrict__ b_ln, float* __restrict__ out) {
  __shared__ short Bs[128][136];  // Bq, then reused for W_eff
  __shared__ short Qs[128][136];  // softmaxed q, row-major [token][d]
  __shared__ float2 red[128][2];

  int tid = threadIdx.x;
  int rowBase = blockIdx.x * 128;
  int b = rowBase >> 12;

  { // stage Bq (wT part 0)
#pragma unroll
    for (int i = 0; i < 8; ++i) {
      int idx = i * 256 + tid;
      int n = idx >> 4;
      int k8 = (idx & 15) << 3;
      *(short8_t*)&Bs[n][k8] = *(const short8_t*)(wT + (size_t)n * 128 + k8);
    }
  }

  // prefetch W_eff[b] into registers (hides latency under GEMM1)
  short8_t b2reg[8];
  {
    const unsigned short* bb = weffT + (size_t)b * 16384;
#pragma unroll
    for (int i = 0; i < 8; ++i) {
      int idx = i * 256 + tid;
      int n = idx >> 4;
      int k8 = (idx & 15) << 3;
      b2reg[i] = *(const short8_t*)(bb + (size_t)n * 128 + k8);
    }
  }

  int lane = tid & 63;
  int wv = tid >> 6;
  int wr = wv >> 1, wc = wv & 1;
  int lr = lane & 15;
  int kg = lane >> 4;

  // A fragments from x
  short8_t abf[4][4];  // [kk][mf]
  {
    const float* ap = x + (size_t)(rowBase + wr * 64 + lr) * 128 + kg * 8;
#pragma unroll
    for (int mf = 0; mf < 4; ++mf) {
      const float* r = ap + (size_t)mf * 16 * 128;
#pragma unroll
      for (int kk = 0; kk < 4; ++kk)
        abf[kk][mf] = trunc8(*(const float4*)(r + kk * 32),
                             *(const float4*)(r + kk * 32 + 4));
    }
  }
  __syncthreads();  // Bq staged

  f32x4 acc[4][4] = {};
#pragma unroll
  for (int kk = 0; kk < 4; ++kk) {
    short8_t bf[4];
#pragma unroll
    for (int nf = 0; nf < 4; ++nf)
      bf[nf] = *(const short8_t*)&Bs[wc * 64 + nf * 16 + lr][kk * 32 + kg * 8];
#pragma unroll
    for (int mf = 0; mf < 4; ++mf)
#pragma unroll
      for (int nf = 0; nf < 4; ++nf)
        acc[mf][nf] = __builtin_amdgcn_mfma_f32_16x16x32_bf16(abf[kk][mf], bf[nf], acc[mf][nf], 0, 0, 0);
  }

  // softmax over d(32) per token, * scale -> Qs LDS (bf16)
#pragma unroll
  for (int hg = 0; hg < 2; ++hg) {
#pragma unroll
    for (int mf = 0; mf < 4; ++mf) {
#pragma unroll
      for (int j = 0; j < 4; ++j) {
        float v0 = acc[mf][hg * 2][j], v1 = acc[mf][hg * 2 + 1][j];
        float m = fmaxf(v0, v1);
#pragma unroll
        for (int d = 1; d < 16; d <<= 1) m = fmaxf(m, __shfl_xor(m, d, 64));
        float e0 = __expf(v0 - m), e1 = __expf(v1 - m);
        float s = e0 + e1;
#pragma unroll
        for (int d = 1; d < 16; d <<= 1) s += __shfl_xor(s, d, 64);
        float inv = SCALE_Q / s;
        int r = wr * 64 + mf * 16 + kg * 4 + j;
        int c0 = wc * 64 + hg * 32 + lr;
        Qs[r][c0] = (short)f2bf(e0 * inv);
        Qs[r][c0 + 16] = (short)f2bf(e1 * inv);
      }
    }
  }
  __syncthreads();  // Bq dead, Qs complete

  { // write prefetched W_eff into Bs
#pragma unroll
    for (int i = 0; i < 8; ++i) {
      int idx = i * 256 + tid;
      int n = idx >> 4;
      int k8 = (idx & 15) << 3;
      *(short8_t*)&Bs[n][k8] = b2reg[i];
    }
  }
  __syncthreads();  // Bs=W_eff, Qs ready

  f32x4 acc2[4][4] = {};
#pragma unroll
  for (int kk = 0; kk < 4; ++kk) {
    short8_t a2[4], bf[4];
#pragma unroll
    for (int mf = 0; mf < 4; ++mf)
      a2[mf] = *(const short8_t*)&Qs[wr * 64 + mf * 16 + lr][kk * 32 + kg * 8];
#pragma unroll
    for (int nf = 0; nf < 4; ++nf)
      bf[nf] = *(const short8_t*)&Bs[wc * 64 + nf * 16 + lr][kk * 32 + kg * 8];
#pragma unroll
    for (int mf = 0; mf < 4; ++mf)
#pragma unroll
      for (int nf = 0; nf < 4; ++nf)
        acc2[mf][nf] = __builtin_amdgcn_mfma_f32_16x16x32_bf16(a2[mf], bf[nf], acc2[mf][nf], 0, 0, 0);
  }

  // bias + LayerNorm epilogue
  int colc[4]; float bo[4], gl[4], bl[4];
#pragma unroll
  for (int nf = 0; nf < 4; ++nf) {
    int c = wc * 64 + nf * 16 + lr;
    colc[nf] = c; bo[nf] = b_out[c]; gl[nf] = g_ln[c]; bl[nf] = b_ln[c];
  }
#pragma unroll
  for (int mf = 0; mf < 4; ++mf)
#pragma unroll
    for (int nf = 0; nf < 4; ++nf)
#pragma unroll
      for (int j = 0; j < 4; ++j) acc2[mf][nf][j] += bo[nf];

#pragma unroll
  for (int mf = 0; mf < 4; ++mf) {
    float s[4] = {0, 0, 0, 0}, q[4] = {0, 0, 0, 0};
#pragma unroll
    for (int nf = 0; nf < 4; ++nf)
#pragma unroll
      for (int j = 0; j < 4; ++j) {
        float v = acc2[mf][nf][j];
        s[j] += v; q[j] += v * v;
      }
#pragma unroll
    for (int j = 0; j < 4; ++j) {
#pragma unroll
      for (int d = 1; d < 16; d <<= 1) {
        s[j] += __shfl_xor(s[j], d, 64);
        q[j] += __shfl_xor(q[j], d, 64);
      }
    }
    if (lr == 0) {
#pragma unroll
      for (int j = 0; j < 4; ++j)
        red[wr * 64 + mf * 16 + kg * 4 + j][wc] = make_float2(s[j], q[j]);
    }
  }
  __syncthreads();
#pragma unroll
  for (int mf = 0; mf < 4; ++mf) {
#pragma unroll
    for (int j = 0; j < 4; ++j) {
      int rloc = wr * 64 + mf * 16 + kg * 4 + j;
      float2 r0 = red[rloc][0], r1 = red[rloc][1];
      float mean = (r0.x + r1.x) * (1.0f / 128.0f);
      float var = (r0.y + r1.y) * (1.0f / 128.0f) - mean * mean;
      float rstd = rsqrtf(var + EPS_LN);
      size_t ro = (size_t)(rowBase + rloc) * 128;
#pragma unroll
      for (int nf = 0; nf < 4; ++nf)
        out[ro + colc[nf]] = (acc2[mf][nf][j] - mean) * rstd * gl[nf] + bl[nf];
    }
  }
}

extern "C" void kernel_launch(void* const* d_in, const int* in_sizes, int n_in,
                              void* d_out, int out_size, void* d_ws, size_t ws_size,
                              hipStream_t stream) {
  const float* x     = (const float*)d_in[0];
  const float* w_qkv = (const float*)d_in[1];
  const float* w_out = (const float*)d_in[2];
  const float* b_out = (const float*)d_in[3];
  const float* g_ln  = (const float*)d_in[4];
  const float* b_ln  = (const float*)d_in[5];
  float* out = (float*)d_out;

  char* ws = (char*)d_ws;
  unsigned short* wqkvT = (unsigned short*)(ws + 0);        // 96 KB bf16 [384][128]
  float* ctxp           = (float*)(ws + 131072);            // 8 MB [512][4][32][32]
  float* ksump          = (float*)(ws + 131072 + 8388608);  // 256 KB [512][128]
  unsigned short* weffT = (unsigned short*)(ws + 131072 + 8388608 + 262144); // 512 KB

  k_transpose_wqkv<<<192, 256, 0, stream>>>(w_qkv, wqkvT);
  k_kv_ctx<<<512, 256, 0, stream>>>(x, wqkvT, ctxp, ksump);
  k_weff<<<16, 256, 0, stream>>>(ctxp, ksump, w_out, weffT);
  k_qout_ln<<<512, 256, 0, stream>>>(x, wqkvT, weffT, b_out, g_ln, b_ln, out);
}

// Round 4
// 62.163 us; speedup vs baseline: 2.2225x; 1.1202x over previous
//
#include <hip/hip_runtime.h>
#include <hip/hip_bf16.h>
#include <cstddef>
#include <cstdint>

// LinearAttention fused pipeline, MI355X gfx950.
// x:[16,64,64,128] f32, w_qkv:[128,384], w_out:[128,128], b_out/g_ln/b_ln:[128]
// Pipeline (x read from HBM exactly once):
//   K1 k_transpose_wqkv: w_qkv -> w_qkv^T bf16
//   K2 k_qkv_ctx: per 128-token tile: A-frags from x once; q,k,v GEMMs with
//      B-frags DIRECT from global (L2-resident weights, no B LDS, 1 barrier).
//      exp(k),v -> LDS transpose -> per-head ctx[32][32] partial MFMA + ksum.
//      q -> softmax(d)*scale (no max pass) -> qs bf16 to HBM.
//   K3 k_weff64: per (b,h): reduce ctx partials, ctxn=ctx/ksum,
//      W_eff^T[b][j][h*32+d] = sum_e ctxn[d][e]*wout[h*32+e][j]  (bf16)
//   K4 k_out_ln: out = LN( qs @ W_eff[b] + b_out ). No LDS, no barriers:
//      wave owns 32 rows x all 128 cols; LN closes in-wave via shfl.

typedef __attribute__((ext_vector_type(8))) short short8_t;
typedef __attribute__((ext_vector_type(4))) float f32x4;

#define SCALE_Q 0.17677669529663687f
#define EPS_LN 1e-5f

__device__ __forceinline__ unsigned short f2bf(float f) {
  union { float f; unsigned u; } v; v.f = f;
  unsigned r = (v.u + 0x7FFFu + ((v.u >> 16) & 1u)) >> 16;
  return (unsigned short)r;
}
__device__ __forceinline__ float bf2f(unsigned short u) {
  union { float f; unsigned u; } v; v.u = ((unsigned)u) << 16;
  return v.f;
}

// pack 8 f32 -> 8 bf16 by truncation: 4x v_perm_b32
__device__ __forceinline__ short8_t trunc8(float4 lo, float4 hi) {
  union { float4 f; unsigned u[4]; } a, b;
  union { unsigned u[4]; short8_t s; } r;
  a.f = lo; b.f = hi;
  r.u[0] = __builtin_amdgcn_perm(a.u[1], a.u[0], 0x07060302);
  r.u[1] = __builtin_amdgcn_perm(a.u[3], a.u[2], 0x07060302);
  r.u[2] = __builtin_amdgcn_perm(b.u[1], b.u[0], 0x07060302);
  r.u[3] = __builtin_amdgcn_perm(b.u[3], b.u[2], 0x07060302);
  return r.s;
}

// ---------------- K1: transpose + bf16 convert w_qkv [128][384] -> [384][128]
__global__ void k_transpose_wqkv(const float* __restrict__ w,
                                 unsigned short* __restrict__ wT) {
  int idx = blockIdx.x * 256 + threadIdx.x;   // 49152 total
  int k = idx / 384;
  int c = idx - k * 384;
  wT[c * 128 + k] = f2bf(w[idx]);
}

// ---------------- K2: q+k+v GEMMs + ctx partial + softmaxed q out
// grid 512 (one per 128-token tile).
__global__ __launch_bounds__(256, 2)
void k_qkv_ctx(const float* __restrict__ x, const unsigned short* __restrict__ wT,
               float* __restrict__ ctxp, float* __restrict__ ksump,
               unsigned short* __restrict__ qs) {
  __shared__ short ekT[128][136];  // exp(k) transposed [d][token]
  __shared__ short vT[128][136];   // v transposed [e][token]

  int tid = threadIdx.x;
  int rb = blockIdx.x;
  int rowBase = rb * 128;

  int lane = tid & 63;
  int wv = tid >> 6;
  int wr = wv >> 1, wc = wv & 1;
  int lr = lane & 15;
  int kg = lane >> 4;

  // A fragments: load x f32, truncate to bf16 once; reused by q,k,v GEMMs
  short8_t abf[4][4];  // [kk][mf]
  {
    const float* ap = x + (size_t)(rowBase + wr * 64 + lr) * 128 + kg * 8;
#pragma unroll
    for (int mf = 0; mf < 4; ++mf) {
      const float* r = ap + (size_t)mf * 16 * 128;
#pragma unroll
      for (int kk = 0; kk < 4; ++kk)
        abf[kk][mf] = trunc8(*(const float4*)(r + kk * 32),
                             *(const float4*)(r + kk * 32 + 4));
    }
  }

  const unsigned short* wq = wT;
  const unsigned short* wk = wT + 16384;
  const unsigned short* wvv = wT + 32768;
  int bRow[4];
#pragma unroll
  for (int nf = 0; nf < 4; ++nf) bRow[nf] = (wc * 64 + nf * 16 + lr) * 128;

  // ---- k GEMM (B frags direct from global/L2) -> exp -> ekT
  {
    f32x4 acc[4][4] = {};
#pragma unroll
    for (int kk = 0; kk < 4; ++kk) {
      short8_t bf[4];
#pragma unroll
      for (int nf = 0; nf < 4; ++nf)
        bf[nf] = *(const short8_t*)(wk + bRow[nf] + kk * 32 + kg * 8);
#pragma unroll
      for (int mf = 0; mf < 4; ++mf)
#pragma unroll
        for (int nf = 0; nf < 4; ++nf)
          acc[mf][nf] = __builtin_amdgcn_mfma_f32_16x16x32_bf16(abf[kk][mf], bf[nf], acc[mf][nf], 0, 0, 0);
    }
#pragma unroll
    for (int mf = 0; mf < 4; ++mf) {
      int t0 = wr * 64 + mf * 16 + kg * 4;
#pragma unroll
      for (int nf = 0; nf < 4; ++nf) {
        unsigned s0 = f2bf(__expf(acc[mf][nf][0])), s1 = f2bf(__expf(acc[mf][nf][1]));
        unsigned s2 = f2bf(__expf(acc[mf][nf][2])), s3 = f2bf(__expf(acc[mf][nf][3]));
        uint2 p; p.x = s0 | (s1 << 16); p.y = s2 | (s3 << 16);
        *(uint2*)&ekT[wc * 64 + nf * 16 + lr][t0] = p;
      }
    }
  }
  // ---- v GEMM -> vT
  {
    f32x4 acc[4][4] = {};
#pragma unroll
    for (int kk = 0; kk < 4; ++kk) {
      short8_t bf[4];
#pragma unroll
      for (int nf = 0; nf < 4; ++nf)
        bf[nf] = *(const short8_t*)(wvv + bRow[nf] + kk * 32 + kg * 8);
#pragma unroll
      for (int mf = 0; mf < 4; ++mf)
#pragma unroll
        for (int nf = 0; nf < 4; ++nf)
          acc[mf][nf] = __builtin_amdgcn_mfma_f32_16x16x32_bf16(abf[kk][mf], bf[nf], acc[mf][nf], 0, 0, 0);
    }
#pragma unroll
    for (int mf = 0; mf < 4; ++mf) {
      int t0 = wr * 64 + mf * 16 + kg * 4;
#pragma unroll
      for (int nf = 0; nf < 4; ++nf) {
        unsigned s0 = f2bf(acc[mf][nf][0]), s1 = f2bf(acc[mf][nf][1]);
        unsigned s2 = f2bf(acc[mf][nf][2]), s3 = f2bf(acc[mf][nf][3]);
        uint2 p; p.x = s0 | (s1 << 16); p.y = s2 | (s3 << 16);
        *(uint2*)&vT[wc * 64 + nf * 16 + lr][t0] = p;
      }
    }
  }

  // ---- q GEMM (before barrier; LDS untouched)
  f32x4 qacc[4][4] = {};
#pragma unroll
  for (int kk = 0; kk < 4; ++kk) {
    short8_t bf[4];
#pragma unroll
    for (int nf = 0; nf < 4; ++nf)
      bf[nf] = *(const short8_t*)(wq + bRow[nf] + kk * 32 + kg * 8);
#pragma unroll
    for (int mf = 0; mf < 4; ++mf)
#pragma unroll
      for (int nf = 0; nf < 4; ++nf)
        qacc[mf][nf] = __builtin_amdgcn_mfma_f32_16x16x32_bf16(abf[kk][mf], bf[nf], qacc[mf][nf], 0, 0, 0);
  }

  __syncthreads();  // ekT/vT complete

  // ---- per-head ctx MFMA: wave wv = head h
  {
    int h = wv;
    f32x4 c2[2][2] = {};
#pragma unroll
    for (int kk = 0; kk < 4; ++kk) {
      short8_t a2[2], b2[2];
#pragma unroll
      for (int m2 = 0; m2 < 2; ++m2)
        a2[m2] = *(const short8_t*)&ekT[h * 32 + m2 * 16 + lr][kk * 32 + kg * 8];
#pragma unroll
      for (int n2 = 0; n2 < 2; ++n2)
        b2[n2] = *(const short8_t*)&vT[h * 32 + n2 * 16 + lr][kk * 32 + kg * 8];
#pragma unroll
      for (int m2 = 0; m2 < 2; ++m2)
#pragma unroll
        for (int n2 = 0; n2 < 2; ++n2)
          c2[m2][n2] = __builtin_amdgcn_mfma_f32_16x16x32_bf16(a2[m2], b2[n2], c2[m2][n2], 0, 0, 0);
    }
    float* cp = ctxp + ((size_t)rb * 4 + h) * 1024;
#pragma unroll
    for (int m2 = 0; m2 < 2; ++m2)
#pragma unroll
      for (int n2 = 0; n2 < 2; ++n2)
#pragma unroll
        for (int j = 0; j < 4; ++j)
          cp[(m2 * 16 + kg * 4 + j) * 32 + n2 * 16 + lr] = c2[m2][n2][j];
  }

  // ---- ksum partial: threads 0..127 sum ekT[channel][0..127]
  if (tid < 128) {
    float s = 0;
#pragma unroll
    for (int t8 = 0; t8 < 128; t8 += 8) {
      short8_t v8 = *(const short8_t*)&ekT[tid][t8];
#pragma unroll
      for (int i = 0; i < 8; ++i) s += bf2f((unsigned short)v8[i]);
    }
    ksump[(size_t)rb * 128 + tid] = s;
  }

  // ---- q softmax over d(32) (no max pass: |q| <= ~4) -> qs bf16
#pragma unroll
  for (int hg = 0; hg < 2; ++hg) {
#pragma unroll
    for (int mf = 0; mf < 4; ++mf) {
#pragma unroll
      for (int j = 0; j < 4; ++j) {
        float e0 = __expf(qacc[mf][hg * 2][j]);
        float e1 = __expf(qacc[mf][hg * 2 + 1][j]);
        float s = e0 + e1;
#pragma unroll
        for (int d = 1; d < 16; d <<= 1) s += __shfl_xor(s, d, 64);
        float inv = SCALE_Q / s;
        int tok = rowBase + wr * 64 + mf * 16 + kg * 4 + j;
        int hd = wc * 64 + hg * 32 + lr;
        qs[(size_t)tok * 128 + hd] = f2bf(e0 * inv);
        qs[(size_t)tok * 128 + hd + 16] = f2bf(e1 * inv);
      }
    }
  }
}

// ---------------- K3: per (b,h) reduce partials + build W_eff^T cols
// grid 64. weffT[b][j][h*32+d] = sum_e (ctx[d][e]/ksum[d]) * wout[h*32+e][j]
__global__ __launch_bounds__(256, 4)
void k_weff64(const float* __restrict__ ctxp, const float* __restrict__ ksump,
              const float* __restrict__ wout, unsigned short* __restrict__ weffT) {
  __shared__ float wo[32][128];  // wout rows h*32+e
  __shared__ float cn[32][32];   // ctxn[d][e]
  __shared__ float ksh[32];
  int tid = threadIdx.x;
  int b = blockIdx.x >> 2, h = blockIdx.x & 3;

#pragma unroll
  for (int i = 0; i < 16; ++i) {
    int idx = i * 256 + tid;
    int e = idx >> 7, jj = idx & 127;
    wo[e][jj] = wout[(h * 32 + e) * 128 + jj];
  }
  if (tid < 32) {
    float s = 0;
    for (int c = 0; c < 32; ++c)
      s += ksump[(size_t)(b * 32 + c) * 128 + h * 32 + tid];
    ksh[tid] = s;
  }
  __syncthreads();
#pragma unroll
  for (int i = 0; i < 4; ++i) {
    int idx = i * 256 + tid;
    int d = idx >> 5, e = idx & 31;
    float s = 0;
    for (int c = 0; c < 32; ++c)
      s += ctxp[((size_t)(b * 32 + c) * 4 + h) * 1024 + idx];
    cn[d][e] = s / ksh[d];
  }
  __syncthreads();

  int j = tid >> 1, dg = tid & 1;
  unsigned short acc16[16];
#pragma unroll
  for (int dd = 0; dd < 16; ++dd) {
    int d = dg * 16 + dd;
    float s = 0;
#pragma unroll
    for (int e = 0; e < 32; ++e) s += cn[d][e] * wo[e][j];
    acc16[dd] = f2bf(s);
  }
  unsigned short* outp = weffT + (size_t)b * 16384 + j * 128 + h * 32 + dg * 16;
  *(short8_t*)outp = *(short8_t*)&acc16[0];
  *(short8_t*)(outp + 8) = *(short8_t*)&acc16[8];
}

// ---------------- K4: out = LN( qs @ W_eff[b] + b_out )  — no LDS, no barriers
// grid 512; wave w owns rows w*32..w*32+31, all 128 cols (nf 0..7).
__global__ __launch_bounds__(256, 2)
void k_out_ln(const unsigned short* __restrict__ qs, const unsigned short* __restrict__ weffT,
              const float* __restrict__ b_out, const float* __restrict__ g_ln,
              const float* __restrict__ b_ln, float* __restrict__ out) {
  int tid = threadIdx.x;
  int rowBase = blockIdx.x * 128;
  int b = rowBase >> 12;
  int lane = tid & 63;
  int w = tid >> 6;
  int lr = lane & 15;
  int kg = lane >> 4;

  const unsigned short* bb = weffT + (size_t)b * 16384;

  // A fragments from qs (bf16, row-major [token][hd])
  short8_t a[2][4];  // [mf][kk]
  {
    const unsigned short* ap = qs + (size_t)(rowBase + w * 32 + lr) * 128 + kg * 8;
#pragma unroll
    for (int mf = 0; mf < 2; ++mf)
#pragma unroll
      for (int kk = 0; kk < 4; ++kk)
        a[mf][kk] = *(const short8_t*)(ap + (size_t)mf * 16 * 128 + kk * 32);
  }

  f32x4 acc[2][8] = {};
#pragma unroll
  for (int kk = 0; kk < 4; ++kk) {
    short8_t bf[8];
#pragma unroll
    for (int nf = 0; nf < 8; ++nf)
      bf[nf] = *(const short8_t*)(bb + (size_t)(nf * 16 + lr) * 128 + kk * 32 + kg * 8);
#pragma unroll
    for (int mf = 0; mf < 2; ++mf)
#pragma unroll
      for (int nf = 0; nf < 8; ++nf)
        acc[mf][nf] = __builtin_amdgcn_mfma_f32_16x16x32_bf16(a[mf][kk], bf[nf], acc[mf][nf], 0, 0, 0);
  }

  float bo[8], gl[8], bl[8];
#pragma unroll
  for (int nf = 0; nf < 8; ++nf) {
    int c = nf * 16 + lr;
    bo[nf] = b_out[c]; gl[nf] = g_ln[c]; bl[nf] = b_ln[c];
  }
#pragma unroll
  for (int mf = 0; mf < 2; ++mf)
#pragma unroll
    for (int nf = 0; nf < 8; ++nf)
#pragma unroll
      for (int j = 0; j < 4; ++j) acc[mf][nf][j] += bo[nf];

#pragma unroll
  for (int mf = 0; mf < 2; ++mf) {
    float s[4] = {0, 0, 0, 0}, q[4] = {0, 0, 0, 0};
#pragma unroll
    for (int nf = 0; nf < 8; ++nf)
#pragma unroll
      for (int j = 0; j < 4; ++j) {
        float v = acc[mf][nf][j];
        s[j] += v; q[j] += v * v;
      }
#pragma unroll
    for (int j = 0; j < 4; ++j) {
#pragma unroll
      for (int d = 1; d < 16; d <<= 1) {
        s[j] += __shfl_xor(s[j], d, 64);
        q[j] += __shfl_xor(q[j], d, 64);
      }
    }
#pragma unroll
    for (int j = 0; j < 4; ++j) {
      float mean = s[j] * (1.0f / 128.0f);
      float var = q[j] * (1.0f / 128.0f) - mean * mean;
      float rstd = rsqrtf(var + EPS_LN);
      size_t ro = (size_t)(rowBase + w * 32 + mf * 16 + kg * 4 + j) * 128;
#pragma unroll
      for (int nf = 0; nf < 8; ++nf)
        out[ro + nf * 16 + lr] = (acc[mf][nf][j] - mean) * rstd * gl[nf] + bl[nf];
    }
  }
}

extern "C" void kernel_launch(void* const* d_in, const int* in_sizes, int n_in,
                              void* d_out, int out_size, void* d_ws, size_t ws_size,
                              hipStream_t stream) {
  const float* x     = (const float*)d_in[0];
  const float* w_qkv = (const float*)d_in[1];
  const float* w_out = (const float*)d_in[2];
  const float* b_out = (const float*)d_in[3];
  const float* g_ln  = (const float*)d_in[4];
  const float* b_ln  = (const float*)d_in[5];
  float* out = (float*)d_out;

  char* ws = (char*)d_ws;
  unsigned short* wqkvT = (unsigned short*)(ws + 0);                  // 96 KB
  float* ctxp           = (float*)(ws + 131072);                     // 8 MB [512][4][32][32]
  float* ksump          = (float*)(ws + 131072 + 8388608);           // 256 KB [512][128]
  unsigned short* weffT = (unsigned short*)(ws + 131072 + 8388608 + 262144);  // 512 KB
  unsigned short* qs    = (unsigned short*)(ws + 131072 + 8388608 + 262144 + 524288); // 16 MB

  k_transpose_wqkv<<<192, 256, 0, stream>>>(w_qkv, wqkvT);
  k_qkv_ctx<<<512, 256, 0, stream>>>(x, wqkvT, ctxp, ksump, qs);
  k_weff64<<<64, 256, 0, stream>>>(ctxp, ksump, w_out, weffT);
  k_out_ln<<<512, 256, 0, stream>>>(qs, weffT, b_out, g_ln, b_ln, out);
}